// Round 2
// baseline (492.779 us; speedup 1.0000x reference)
//
#include <hip/hip_runtime.h>

typedef short short8  __attribute__((ext_vector_type(8)));
typedef short short4v __attribute__((ext_vector_type(4)));
typedef float f32x4   __attribute__((ext_vector_type(4)));

#define MFMA_BF16(A,B,C) __builtin_amdgcn_mfma_f32_16x16x32_bf16((A),(B),(C),0,0,0)

__device__ __forceinline__ short bf16bits(float f){
  return (short)__builtin_bit_cast(unsigned short, static_cast<__bf16>(f));
}

// ---------------- mask preprocessing ----------------
// region_masks: [R=2][T=121][MH=88][MW=160] (B=1). Latent grid 16x44x80.
// Trilinear (half-pixel): t=0 -> frame 0; t>=1 -> avg frames (8t-4, 8t-3).
// H,W downsample by 2 -> 2x2 average. allowed bits: b0=global, b1=region0, b2=region1.
__global__ __launch_bounds__(256) void maskprep_kernel(const float* __restrict__ rm,
                                                       unsigned* __restrict__ allowed){
  int s = blockIdx.x*256 + threadIdx.x;
  if (s >= 56320) return;
  int t = s / 3520;
  int rem = s - t*3520;
  int i = rem / 80;
  int j = rem - i*80;
  int y = 2*i, x = 2*j;
  bool bin[2];
  #pragma unroll
  for (int r=0;r<2;r++){
    const float* base = rm + (size_t)r*121*88*160;
    float acc;
    if (t == 0){
      const float* p0 = base + (size_t)(0*88 + y)*160 + x;
      acc = 0.25f*(p0[0]+p0[1]+p0[160]+p0[161]);
    } else {
      const float* pa = base + (size_t)((8*t-4)*88 + y)*160 + x;
      const float* pb = base + (size_t)((8*t-3)*88 + y)*160 + x;
      acc = 0.125f*(pa[0]+pa[1]+pa[160]+pa[161] + pb[0]+pb[1]+pb[160]+pb[161]);
    }
    bin[r] = acc > 0.5f;
  }
  unsigned bits = (bin[0]||bin[1]) ? 0u : 1u;
  if (bin[0]) bits |= 2u;
  if (bin[1]) bits |= 4u;
  allowed[s] = bits;
}

// ---------------- K/V preprocessing ----------------
// 24 blocks, one (h,seg) 128x64 tile each. Kb[h][seg][p][d] written directly
// (coalesced); V transposed through LDS so VT[h][d][seg*128+p] rows are
// written as contiguous 256B runs (was a 2B-per-line scatter before).
__global__ __launch_bounds__(256) void kvprep_kernel(const float* __restrict__ k,
                                                     const float* __restrict__ v,
                                                     const float* __restrict__ rk,
                                                     const float* __restrict__ rv,
                                                     unsigned short* __restrict__ Kb,
                                                     unsigned short* __restrict__ VT){
  const int b   = blockIdx.x;      // h*3 + seg
  const int h   = b / 3;
  const int seg = b - h*3;
  const float* ksrc = (seg == 0) ? k : rk + (size_t)(seg-1)*65536;
  const float* vsrc = (seg == 0) ? v : rv + (size_t)(seg-1)*65536;

  __shared__ unsigned short vt[64][130];   // [d][p], +2 pad

  #pragma unroll
  for (int i=0;i<32;i++){
    int e = i*256 + threadIdx.x;   // e = p*64 + d
    int p = e >> 6, d = e & 63;
    size_t src = ((size_t)p*8 + h)*64 + d;
    Kb[((size_t)b*128 + p)*64 + d] = (unsigned short)bf16bits(ksrc[src]);
    vt[d][p] = (unsigned short)bf16bits(vsrc[src]);
  }
  __syncthreads();
  #pragma unroll
  for (int i=0;i<32;i++){
    int e = i*256 + threadIdx.x;   // e = d*128 + p
    int d = e >> 7, p = e & 127;
    VT[((size_t)h*64 + d)*384 + seg*128 + p] = vt[d][p];
  }
}

// ---------------- fused regional+base attention ----------------
// Transposed compute: S^T = K·Q^T. C-layout: lane holds query col = lane&15
// (one query per lane -> scalar gating, xor16/32 softmax reduce), key rows =
// quad*4+reg (+16*tile). scale 0.125 folded into q->bf16 (exact, pow2).
// Softmax: per-segment unmasked maxes/sums, ONE exp pass (97 exps vs 192):
// seg0 exps taken vs mbase, regional seg0 contribution derived via
// scaleA = exp(mbase-mreg). Merged coeff = e * g[seg], g per-lane scalar.
// P^T -> per-wave-private LDS (no barrier needed) -> out^T = V^T·P^T.
__global__ __launch_bounds__(256) void attn_kernel(const float* __restrict__ q,
                                                   const unsigned* __restrict__ allowed,
                                                   const unsigned short* __restrict__ Kb,
                                                   const unsigned short* __restrict__ VT,
                                                   float* __restrict__ out){
  constexpr int H = 8, D = 64;
  const int h    = blockIdx.y;
  const int wave = threadIdx.x >> 6;
  const int lane = threadIdx.x & 63;
  const int c    = lane & 15;        // query col
  const int Q    = lane >> 4;        // quad
  const int s    = blockIdx.x*64 + wave*16 + c;

  __shared__ __align__(16) unsigned short pt[4*16*392];
  unsigned short* myrow = pt + wave*(16*392) + c*392;

  const unsigned ab = allowed[s];    // hoisted early

  // ---- Q fragments (B-operand): lane d = Q*8+j (+32 for second frag); *0.125
  const float* qp = q + ((size_t)s*H + h)*D + Q*8;
  f32x4 qa = *(const f32x4*)(qp);
  f32x4 qb = *(const f32x4*)(qp + 4);
  f32x4 qc_ = *(const f32x4*)(qp + 32);
  f32x4 qd = *(const f32x4*)(qp + 36);
  short8 qf0, qf1;
  #pragma unroll
  for (int jj=0;jj<4;jj++){
    qf0[jj]   = bf16bits(qa[jj]*0.125f);
    qf0[4+jj] = bf16bits(qb[jj]*0.125f);
    qf1[jj]   = bf16bits(qc_[jj]*0.125f);
    qf1[4+jj] = bf16bits(qd[jj]*0.125f);
  }

  // ---- scores (pre-scaled) + per-segment unmasked max
  const unsigned short* kbase = Kb + (size_t)h*3*128*64;
  float sc[24][4];
  float mseg[3] = {-3.0e38f, -3.0e38f, -3.0e38f};
  #pragma unroll
  for (int t=0;t<24;t++){
    const unsigned short* kp = kbase + (t*16 + c)*64 + Q*8;
    short8 kf0 = *(const short8*)(kp);
    short8 kf1 = *(const short8*)(kp + 32);
    f32x4 acc = {0.f,0.f,0.f,0.f};
    acc = MFMA_BF16(kf0, qf0, acc);
    acc = MFMA_BF16(kf1, qf1, acc);
    #pragma unroll
    for (int r=0;r<4;r++){ sc[t][r] = acc[r]; mseg[t>>3] = fmaxf(mseg[t>>3], acc[r]); }
  }

  const bool A0 = ab & 1u, A1 = ab & 2u, A2 = ab & 4u;
  float mreg = fmaxf(fmaxf(A0 ? mseg[0] : -3.0e38f, A1 ? mseg[1] : -3.0e38f),
                     A2 ? mseg[2] : -3.0e38f);
  mreg  = fmaxf(mreg,  __shfl_xor(mreg, 16));
  mreg  = fmaxf(mreg,  __shfl_xor(mreg, 32));
  float mbase = mseg[0];
  mbase = fmaxf(mbase, __shfl_xor(mbase, 16));
  mbase = fmaxf(mbase, __shfl_xor(mbase, 32));

  // ---- single exp pass: seg0 vs mbase, segs 1/2 vs mreg; per-seg sums
  float l0 = 0.f, l1 = 0.f, l2 = 0.f;
  #pragma unroll
  for (int t=0;t<8;t++)
    #pragma unroll
    for (int r=0;r<4;r++){ float e = __expf(sc[t][r] - mbase); sc[t][r] = e; l0 += e; }
  #pragma unroll
  for (int t=8;t<16;t++)
    #pragma unroll
    for (int r=0;r<4;r++){ float e = __expf(sc[t][r] - mreg); sc[t][r] = e; l1 += e; }
  #pragma unroll
  for (int t=16;t<24;t++)
    #pragma unroll
    for (int r=0;r<4;r++){ float e = __expf(sc[t][r] - mreg); sc[t][r] = e; l2 += e; }

  const float scaleA = __expf(mbase - mreg);   // exp(v-mreg) = exp(v-mbase)*scaleA
  float lreg = (A0 ? scaleA*l0 : 0.f) + (A1 ? l1 : 0.f) + (A2 ? l2 : 0.f);
  lreg += __shfl_xor(lreg, 16);  lreg += __shfl_xor(lreg, 32);
  float lbase = l0;
  lbase += __shfl_xor(lbase, 16); lbase += __shfl_xor(lbase, 32);

  const float invr = 0.5f/lreg, invb = 0.5f/lbase;
  const float g0 = (A0 ? scaleA*invr : 0.f) + invb;
  const float g1 = A1 ? invr : 0.f;
  const float g2 = A2 ? invr : 0.f;

  // ---- merged coefficients -> bf16 -> per-wave LDS P^T[query][key]
  #pragma unroll
  for (int t=0;t<24;t++){
    const float g = (t < 8) ? g0 : ((t < 16) ? g1 : g2);
    short4v pk;
    #pragma unroll
    for (int r=0;r<4;r++) pk[r] = bf16bits(sc[t][r]*g);
    *(short4v*)(myrow + t*16 + Q*4) = pk;
  }
  // no __syncthreads: pt region is per-wave private; lgkmcnt ordering suffices

  // ---- out^T = V^T · P^T : A = V^T-frag (d=m*16+c, key=kc*32+Q*8+j)
  f32x4 acc[4];
  #pragma unroll
  for (int m=0;m<4;m++) acc[m] = (f32x4){0.f,0.f,0.f,0.f};
  const unsigned short* vb = VT + (size_t)h*64*384;
  #pragma unroll
  for (int kc=0;kc<12;kc++){
    short8 pf = *(const short8*)(myrow + kc*32 + Q*8);
    #pragma unroll
    for (int m=0;m<4;m++){
      short8 vf = *(const short8*)(vb + (m*16 + c)*384 + kc*32 + Q*8);
      acc[m] = MFMA_BF16(vf, pf, acc[m]);
    }
  }

  // ---- store: lane holds d = m*16 + Q*4 + r for query s
  float* ob = out + (size_t)s*512 + h*64 + Q*4;
  #pragma unroll
  for (int m=0;m<4;m++) *(f32x4*)(ob + m*16) = acc[m];
}

extern "C" void kernel_launch(void* const* d_in, const int* in_sizes, int n_in,
                              void* d_out, int out_size, void* d_ws, size_t ws_size,
                              hipStream_t stream) {
  const float* q  = (const float*)d_in[0];
  const float* k  = (const float*)d_in[1];
  const float* v  = (const float*)d_in[2];
  const float* rk = (const float*)d_in[3];
  const float* rv = (const float*)d_in[4];
  const float* rm = (const float*)d_in[5];
  float* out = (float*)d_out;

  char* ws = (char*)d_ws;
  unsigned*       allowed = (unsigned*)ws;                           // 225280 B
  unsigned short* Kb      = (unsigned short*)(ws + 225280);          // 393216 B
  unsigned short* VT      = (unsigned short*)(ws + 225280 + 393216); // 393216 B

  maskprep_kernel<<<220, 256, 0, stream>>>(rm, allowed);
  kvprep_kernel<<<24, 256, 0, stream>>>(k, v, rk, rv, Kb, VT);
  dim3 grid(880, 8);
  attn_kernel<<<grid, 256, 0, stream>>>(q, allowed, Kb, VT, out);
}

// Round 3
// 490.854 us; speedup vs baseline: 1.0039x; 1.0039x over previous
//
#include <hip/hip_runtime.h>

typedef short short8  __attribute__((ext_vector_type(8)));
typedef short short4v __attribute__((ext_vector_type(4)));
typedef float f32x4   __attribute__((ext_vector_type(4)));

#define MFMA_BF16(A,B,C) __builtin_amdgcn_mfma_f32_16x16x32_bf16((A),(B),(C),0,0,0)

__device__ __forceinline__ short bf16bits(float f){
  return (short)__builtin_bit_cast(unsigned short, static_cast<__bf16>(f));
}

// ---------------- fused preprocessing ----------------
// Blocks [0,96): K/V prep. 96 = 24 (h,seg) tiles x 4 quarters of 32 p-rows.
//   Kb[h][seg][p][d] bf16 direct (coalesced); V transposed through LDS so
//   VT[h][d][seg*128+p] is written in 64B runs.
// Blocks [96,316): mask prep. region_masks [R=2][121][88][160] -> latent
//   16x44x80. Trilinear half-pixel: t=0 -> frame 0; t>=1 -> avg frames
//   (8t-4, 8t-3); H/W are 2x2 averages. allowed bits: b0=global, b1=r0, b2=r1.
__global__ __launch_bounds__(256) void prep_kernel(const float* __restrict__ k,
                                                   const float* __restrict__ v,
                                                   const float* __restrict__ rk,
                                                   const float* __restrict__ rv,
                                                   const float* __restrict__ rm,
                                                   unsigned short* __restrict__ Kb,
                                                   unsigned short* __restrict__ VT,
                                                   unsigned* __restrict__ allowed){
  if (blockIdx.x < 96){
    const int tile = blockIdx.x >> 2;        // h*3 + seg
    const int p0   = (blockIdx.x & 3) * 32;
    const int h    = tile / 3;
    const int seg  = tile - h*3;
    const float* ksrc = (seg == 0) ? k : rk + (size_t)(seg-1)*65536;
    const float* vsrc = (seg == 0) ? v : rv + (size_t)(seg-1)*65536;

    __shared__ unsigned short vt[64][34];    // [d][p'], +2 pad

    #pragma unroll
    for (int i=0;i<8;i++){
      int e = i*256 + threadIdx.x;           // e = p'*64 + d, 2048 elems
      int p = e >> 6, d = e & 63;
      size_t src = ((size_t)(p0+p)*8 + h)*64 + d;
      Kb[((size_t)tile*128 + p0 + p)*64 + d] = (unsigned short)bf16bits(ksrc[src]);
      vt[d][p] = (unsigned short)bf16bits(vsrc[src]);
    }
    __syncthreads();
    #pragma unroll
    for (int i=0;i<8;i++){
      int e = i*256 + threadIdx.x;           // e = d*32 + p'
      int d = e >> 5, p = e & 31;
      VT[((size_t)h*64 + d)*384 + seg*128 + p0 + p] = vt[d][p];
    }
    return;
  }

  int s = (blockIdx.x - 96)*256 + threadIdx.x;
  if (s >= 56320) return;
  int t = s / 3520;
  int rem = s - t*3520;
  int i = rem / 80;
  int j = rem - i*80;
  int y = 2*i, x = 2*j;
  bool bin[2];
  #pragma unroll
  for (int r=0;r<2;r++){
    const float* base = rm + (size_t)r*121*88*160;
    float acc;
    if (t == 0){
      const float* p0 = base + (size_t)y*160 + x;
      acc = 0.25f*(p0[0]+p0[1]+p0[160]+p0[161]);
    } else {
      const float* pa = base + (size_t)((8*t-4)*88 + y)*160 + x;
      const float* pb = base + (size_t)((8*t-3)*88 + y)*160 + x;
      acc = 0.125f*(pa[0]+pa[1]+pa[160]+pa[161] + pb[0]+pb[1]+pb[160]+pb[161]);
    }
    bin[r] = acc > 0.5f;
  }
  unsigned bits = (bin[0]||bin[1]) ? 0u : 1u;
  if (bin[0]) bits |= 2u;
  if (bin[1]) bits |= 4u;
  allowed[s] = bits;
}

// ---------------- fused regional+base attention ----------------
// Transposed compute: S^T = K·Q^T. C-layout: lane holds query col = lane&15
// (one query per lane -> scalar gating, xor16/32 softmax reduce), key rows =
// quad*4+reg (+16*tile). scale 0.125 folded into q->bf16 (exact, pow2).
// Softmax: per-segment unmasked maxes/sums, one exp pass; merged coeff
// g[seg] per lane. PV is CHUNKED over 32-key chunks through a tiny per-wave
// LDS buffer (16 queries x 32 keys bf16 = 1 KB/wave, 4 KB/block) -- LDS was
// 50 KB before and capped occupancy at 3 blocks/CU (the R1/R2 343us wall).
__global__ __launch_bounds__(256) void attn_kernel(const float* __restrict__ q,
                                                   const unsigned* __restrict__ allowed,
                                                   const unsigned short* __restrict__ Kb,
                                                   const unsigned short* __restrict__ VT,
                                                   float* __restrict__ out){
  constexpr int H = 8, D = 64;
  const int h    = blockIdx.y;
  const int wave = threadIdx.x >> 6;
  const int lane = threadIdx.x & 63;
  const int c    = lane & 15;        // query col
  const int Q    = lane >> 4;        // quad
  const int s    = blockIdx.x*64 + wave*16 + c;

  __shared__ __align__(16) unsigned short pt[4][16][32];   // per-wave chunk buffer

  const unsigned ab = allowed[s];

  // ---- Q fragments (B-operand): lane d = Q*8+j (+32 for second frag); *0.125
  const float* qp = q + ((size_t)s*H + h)*D + Q*8;
  f32x4 qa = *(const f32x4*)(qp);
  f32x4 qb = *(const f32x4*)(qp + 4);
  f32x4 qc_ = *(const f32x4*)(qp + 32);
  f32x4 qd = *(const f32x4*)(qp + 36);
  short8 qf0, qf1;
  #pragma unroll
  for (int jj=0;jj<4;jj++){
    qf0[jj]   = bf16bits(qa[jj]*0.125f);
    qf0[4+jj] = bf16bits(qb[jj]*0.125f);
    qf1[jj]   = bf16bits(qc_[jj]*0.125f);
    qf1[4+jj] = bf16bits(qd[jj]*0.125f);
  }

  // ---- scores (pre-scaled) + per-segment unmasked max
  const unsigned short* kbase = Kb + (size_t)h*3*128*64;
  float sc[24][4];
  float mseg[3] = {-3.0e38f, -3.0e38f, -3.0e38f};
  #pragma unroll
  for (int t=0;t<24;t++){
    const unsigned short* kp = kbase + (t*16 + c)*64 + Q*8;
    short8 kf0 = *(const short8*)(kp);
    short8 kf1 = *(const short8*)(kp + 32);
    f32x4 acc = {0.f,0.f,0.f,0.f};
    acc = MFMA_BF16(kf0, qf0, acc);
    acc = MFMA_BF16(kf1, qf1, acc);
    #pragma unroll
    for (int r=0;r<4;r++){ sc[t][r] = acc[r]; mseg[t>>3] = fmaxf(mseg[t>>3], acc[r]); }
  }

  const bool A0 = ab & 1u, A1 = ab & 2u, A2 = ab & 4u;
  float mreg = fmaxf(fmaxf(A0 ? mseg[0] : -3.0e38f, A1 ? mseg[1] : -3.0e38f),
                     A2 ? mseg[2] : -3.0e38f);
  mreg  = fmaxf(mreg,  __shfl_xor(mreg, 16));
  mreg  = fmaxf(mreg,  __shfl_xor(mreg, 32));
  float mbase = mseg[0];
  mbase = fmaxf(mbase, __shfl_xor(mbase, 16));
  mbase = fmaxf(mbase, __shfl_xor(mbase, 32));

  // ---- single exp pass: seg0 vs mbase, segs 1/2 vs mreg; per-seg sums
  float l0 = 0.f, l1 = 0.f, l2 = 0.f;
  #pragma unroll
  for (int t=0;t<8;t++)
    #pragma unroll
    for (int r=0;r<4;r++){ float e = __expf(sc[t][r] - mbase); sc[t][r] = e; l0 += e; }
  #pragma unroll
  for (int t=8;t<16;t++)
    #pragma unroll
    for (int r=0;r<4;r++){ float e = __expf(sc[t][r] - mreg); sc[t][r] = e; l1 += e; }
  #pragma unroll
  for (int t=16;t<24;t++)
    #pragma unroll
    for (int r=0;r<4;r++){ float e = __expf(sc[t][r] - mreg); sc[t][r] = e; l2 += e; }

  const float scaleA = __expf(mbase - mreg);   // exp(v-mreg) = exp(v-mbase)*scaleA
  float lreg = (A0 ? scaleA*l0 : 0.f) + (A1 ? l1 : 0.f) + (A2 ? l2 : 0.f);
  lreg += __shfl_xor(lreg, 16);  lreg += __shfl_xor(lreg, 32);
  float lbase = l0;
  lbase += __shfl_xor(lbase, 16); lbase += __shfl_xor(lbase, 32);

  const float invr = 0.5f/lreg, invb = 0.5f/lbase;
  const float g0 = (A0 ? scaleA*invr : 0.f) + invb;
  const float g1 = A1 ? invr : 0.f;
  const float g2 = A2 ? invr : 0.f;

  // ---- chunked PV: per 32-key chunk, coeff->bf16 -> per-wave LDS -> B-frag
  // chunk kc covers tiles 2kc,2kc+1; kc 0-3 seg0, 4-7 seg1, 8-11 seg2.
  f32x4 acc[4];
  #pragma unroll
  for (int m=0;m<4;m++) acc[m] = (f32x4){0.f,0.f,0.f,0.f};
  const unsigned short* vb = VT + (size_t)h*64*384;
  #pragma unroll
  for (int kc=0;kc<12;kc++){
    const float g = (kc < 4) ? g0 : ((kc < 8) ? g1 : g2);
    short4v pk0, pk1;
    #pragma unroll
    for (int r=0;r<4;r++){
      pk0[r] = bf16bits(sc[2*kc][r]*g);
      pk1[r] = bf16bits(sc[2*kc+1][r]*g);
    }
    *(short4v*)&pt[wave][c][Q*4]      = pk0;   // keys kc*32 + Q*4+r
    *(short4v*)&pt[wave][c][16 + Q*4] = pk1;   // keys kc*32 + 16 + Q*4+r
    // in-wave cross-quad RAW through LDS: compiler's lgkmcnt ordering suffices
    short8 pf = *(const short8*)&pt[wave][c][Q*8];
    #pragma unroll
    for (int m=0;m<4;m++){
      short8 vf = *(const short8*)(vb + (m*16 + c)*384 + kc*32 + Q*8);
      acc[m] = MFMA_BF16(vf, pf, acc[m]);
    }
  }

  // ---- store: lane holds d = m*16 + Q*4 + r for query s
  float* ob = out + (size_t)s*512 + h*64 + Q*4;
  #pragma unroll
  for (int m=0;m<4;m++) *(f32x4*)(ob + m*16) = acc[m];
}

extern "C" void kernel_launch(void* const* d_in, const int* in_sizes, int n_in,
                              void* d_out, int out_size, void* d_ws, size_t ws_size,
                              hipStream_t stream) {
  const float* q  = (const float*)d_in[0];
  const float* k  = (const float*)d_in[1];
  const float* v  = (const float*)d_in[2];
  const float* rk = (const float*)d_in[3];
  const float* rv = (const float*)d_in[4];
  const float* rm = (const float*)d_in[5];
  float* out = (float*)d_out;

  char* ws = (char*)d_ws;
  unsigned*       allowed = (unsigned*)ws;                           // 225280 B
  unsigned short* Kb      = (unsigned short*)(ws + 225280);          // 393216 B
  unsigned short* VT      = (unsigned short*)(ws + 225280 + 393216); // 393216 B

  prep_kernel<<<316, 256, 0, stream>>>(k, v, rk, rv, rm, Kb, VT, allowed);
  dim3 grid(880, 8);
  attn_kernel<<<grid, 256, 0, stream>>>(q, allowed, Kb, VT, out);
}